// Round 2
// baseline (131.168 us; speedup 1.0000x reference)
//
#include <hip/hip_runtime.h>

// Problem constants (from reference)
#define B_    1024
#define S_    13
#define A_    5
#define C_    20
#define E_    25      // 5 + C
#define CH_   125     // A * E
#define CELLS 169     // S*S
#define TOTAL (B_ * CELLS)   // 173056 = 676 * 256
#define DXY   32.0f   // 416 / 13
#define IMGW  416.0f

__global__ __launch_bounds__(256)
void detection_loss_kernel(const float* __restrict__ pred,
                           const float* __restrict__ yhat,
                           const float* __restrict__ prior,
                           float* __restrict__ out)
{
    const int t = blockIdx.x * 256 + threadIdx.x;

    float local = 0.0f;
    if (t < TOTAL) {
        const int b  = t / CELLS;
        const int ij = t - b * CELLS;
        const int i  = ij / S_;
        const int j  = ij - i * S_;

        const float cx = DXY * (float)j;   // dx * cell_x
        const float cy = DXY * (float)i;   // dy * cell_y

        // ---- ground truth (y_hat[b,i,j,0..5]) : 3x float2, 8B aligned ----
        const float2* yh2 = reinterpret_cast<const float2*>(yhat + (size_t)t * 6);
        const float2 y0 = yh2[0];
        const float2 y1 = yh2[1];
        const float2 y2 = yh2[2];
        const float g_obj = y0.x;
        const float g_tx  = y0.y;
        const float g_ty  = y1.x;
        const float g_tw  = y1.y;
        const float g_th  = y2.x;
        const int   gcls  = (int)(y2.y + 0.5f);

        // match reference op order: dx*cell + dx*t
        const float g_bx = cx + DXY * g_tx;
        const float g_by = cy + DXY * g_ty;
        const float g_bw = g_tw * IMGW;
        const float g_bh = g_th * IMGW;
        const float gx1 = g_bx - 0.5f * g_bw, gx2 = g_bx + 0.5f * g_bw;
        const float gy1 = g_by - 0.5f * g_bh, gy2 = g_by + 0.5f * g_bh;
        const float g_area = g_bw * g_bh;

        // base of this cell's pred data: pred[b, ch, i, j] = pb[ch*CELLS]
        const float* pb = pred + (size_t)b * CH_ * CELLS + ij;

        float best_iou   = -INFINITY;
        float best_err   = 0.0f;
        float nonobj_acc = 0.0f;

        #pragma unroll
        for (int a = 0; a < A_; ++a) {
            const float* pa = pb + (size_t)(a * E_) * CELLS;
            const float p_obj = pa[0 * CELLS];
            const float p_tx  = pa[1 * CELLS];
            const float p_ty  = pa[2 * CELLS];
            const float p_tw  = pa[3 * CELLS];
            const float p_th  = pa[4 * CELLS];

            const float pw0 = prior[2 * a + 0];
            const float ph0 = prior[2 * a + 1];

            const float p_bx = cx + DXY * p_tx;
            const float p_by = cy + DXY * p_ty;
            const float p_bw = pw0 * p_tw * IMGW;
            const float p_bh = ph0 * p_th * IMGW;

            const float px1 = p_bx - 0.5f * p_bw, px2 = p_bx + 0.5f * p_bw;
            const float py1 = p_by - 0.5f * p_bh, py2 = p_by + 0.5f * p_bh;

            float iw = fminf(px2, gx2) - fmaxf(px1, gx1); iw = fmaxf(iw, 0.0f);
            float ih = fminf(py2, gy2) - fmaxf(py1, gy1); ih = fmaxf(ih, 0.0f);
            const float inter = iw * ih;
            const float uni   = p_bw * p_bh + g_area - inter;
            const float iou   = inter / (uni + 1e-6f);

            const float dtx = p_tx - g_tx, dty = p_ty - g_ty;
            const float dtw = p_tw - g_tw, dth = p_th - g_th;
            const float dob = p_obj - iou;
            float err = dtx*dtx + dty*dty + dtw*dtw + dth*dth + dob*dob;

            #pragma unroll
            for (int c = 0; c < C_; ++c) {
                const float pc = pa[(5 + c) * CELLS];
                const float d  = pc - ((c == gcls) ? 1.0f : 0.0f);
                err += d * d;
            }

            // jnp.argmax: first max wins -> strict '>'
            if (iou > best_iou) { best_iou = iou; best_err = err; }
            nonobj_acc += p_obj * p_obj;
        }

        local = (g_obj == 1.0f) ? (5.0f * best_err) : (0.5f * nonobj_acc);
        local *= (1.0f / (float)B_);
    }

    // ---- block reduction: wave64 shuffle -> LDS -> one atomic per block ----
    #pragma unroll
    for (int off = 32; off > 0; off >>= 1)
        local += __shfl_down(local, off, 64);

    __shared__ float wsum[4];
    const int lane = threadIdx.x & 63;
    const int w    = threadIdx.x >> 6;
    if (lane == 0) wsum[w] = local;
    __syncthreads();
    if (threadIdx.x == 0) {
        atomicAdd(out, wsum[0] + wsum[1] + wsum[2] + wsum[3]);
    }
}

extern "C" void kernel_launch(void* const* d_in, const int* in_sizes, int n_in,
                              void* d_out, int out_size, void* d_ws, size_t ws_size,
                              hipStream_t stream) {
    const float* pred  = (const float*)d_in[0];
    const float* yhat  = (const float*)d_in[1];
    const float* prior = (const float*)d_in[2];
    float* out = (float*)d_out;

    // d_out is poisoned (0xAA) before every replay -> zero it in-capture.
    hipMemsetAsync(out, 0, sizeof(float), stream);

    const int blocks = TOTAL / 256;  // 676 exactly
    detection_loss_kernel<<<blocks, 256, 0, stream>>>(pred, yhat, prior, out);
}

// Round 3
// 130.043 us; speedup vs baseline: 1.0086x; 1.0086x over previous
//
#include <hip/hip_runtime.h>

// Problem constants (from reference)
#define B_    1024
#define S_    13
#define A_    5
#define C_    20
#define E_    25      // 5 + C
#define CH_   125     // A * E
#define CELLS 169     // S*S
#define TOTAL (B_ * CELLS)   // 173056 = 676 * 256
#define NBLK  (TOTAL / 256)  // 676
#define DXY   32.0f   // 416 / 13
#define IMGW  416.0f

__global__ __launch_bounds__(256)
void detection_loss_partial(const float* __restrict__ pred,
                            const float* __restrict__ yhat,
                            const float* __restrict__ prior,
                            float* __restrict__ partials)
{
    const int t = blockIdx.x * 256 + threadIdx.x;

    float local = 0.0f;
    {
        const int b  = t / CELLS;
        const int ij = t - b * CELLS;
        const int i  = ij / S_;
        const int j  = ij - i * S_;

        const float cx = DXY * (float)j;   // dx * cell_x
        const float cy = DXY * (float)i;   // dy * cell_y

        // ---- ground truth (y_hat[b,i,j,0..5]) : 3x float2, 8B aligned ----
        const float2* yh2 = reinterpret_cast<const float2*>(yhat + (size_t)t * 6);
        const float2 y0 = yh2[0];
        const float2 y1 = yh2[1];
        const float2 y2 = yh2[2];
        const float g_obj = y0.x;
        const float g_tx  = y0.y;
        const float g_ty  = y1.x;
        const float g_tw  = y1.y;
        const float g_th  = y2.x;
        const int   gcls  = (int)(y2.y + 0.5f);

        // match reference op order: dx*cell + dx*t
        const float g_bx = cx + DXY * g_tx;
        const float g_by = cy + DXY * g_ty;
        const float g_bw = g_tw * IMGW;
        const float g_bh = g_th * IMGW;
        const float gx1 = g_bx - 0.5f * g_bw, gx2 = g_bx + 0.5f * g_bw;
        const float gy1 = g_by - 0.5f * g_bh, gy2 = g_by + 0.5f * g_bh;
        const float g_area = g_bw * g_bh;

        // base of this cell's pred data: pred[b, ch, i, j] = pb[ch*CELLS]
        const float* pb = pred + (size_t)b * CH_ * CELLS + ij;

        float best_iou   = -INFINITY;
        float best_err   = 0.0f;
        float nonobj_acc = 0.0f;

        #pragma unroll
        for (int a = 0; a < A_; ++a) {
            const float* pa = pb + (size_t)(a * E_) * CELLS;
            const float p_obj = pa[0 * CELLS];
            const float p_tx  = pa[1 * CELLS];
            const float p_ty  = pa[2 * CELLS];
            const float p_tw  = pa[3 * CELLS];
            const float p_th  = pa[4 * CELLS];

            const float pw0 = prior[2 * a + 0];
            const float ph0 = prior[2 * a + 1];

            const float p_bx = cx + DXY * p_tx;
            const float p_by = cy + DXY * p_ty;
            const float p_bw = pw0 * p_tw * IMGW;
            const float p_bh = ph0 * p_th * IMGW;

            const float px1 = p_bx - 0.5f * p_bw, px2 = p_bx + 0.5f * p_bw;
            const float py1 = p_by - 0.5f * p_bh, py2 = p_by + 0.5f * p_bh;

            float iw = fminf(px2, gx2) - fmaxf(px1, gx1); iw = fmaxf(iw, 0.0f);
            float ih = fminf(py2, gy2) - fmaxf(py1, gy1); ih = fmaxf(ih, 0.0f);
            const float inter = iw * ih;
            const float uni   = p_bw * p_bh + g_area - inter;
            const float iou   = inter / (uni + 1e-6f);

            const float dtx = p_tx - g_tx, dty = p_ty - g_ty;
            const float dtw = p_tw - g_tw, dth = p_th - g_th;
            const float dob = p_obj - iou;
            float err = dtx*dtx + dty*dty + dtw*dtw + dth*dth + dob*dob;

            #pragma unroll
            for (int c = 0; c < C_; ++c) {
                const float pc = pa[(5 + c) * CELLS];
                const float d  = pc - ((c == gcls) ? 1.0f : 0.0f);
                err += d * d;
            }

            // jnp.argmax: first max wins -> strict '>'
            if (iou > best_iou) { best_iou = iou; best_err = err; }
            nonobj_acc += p_obj * p_obj;
        }

        local = (g_obj == 1.0f) ? (5.0f * best_err) : (0.5f * nonobj_acc);
        local *= (1.0f / (float)B_);
    }

    // ---- block reduction: wave64 shuffle -> LDS -> one plain store per block
    #pragma unroll
    for (int off = 32; off > 0; off >>= 1)
        local += __shfl_down(local, off, 64);

    __shared__ float wsum[4];
    const int lane = threadIdx.x & 63;
    const int w    = threadIdx.x >> 6;
    if (lane == 0) wsum[w] = local;
    __syncthreads();
    if (threadIdx.x == 0) {
        partials[blockIdx.x] = wsum[0] + wsum[1] + wsum[2] + wsum[3];
    }
}

__global__ __launch_bounds__(256)
void detection_loss_final(const float* __restrict__ partials,
                          float* __restrict__ out)
{
    float s = 0.0f;
    for (int k = threadIdx.x; k < NBLK; k += 256)
        s += partials[k];

    #pragma unroll
    for (int off = 32; off > 0; off >>= 1)
        s += __shfl_down(s, off, 64);

    __shared__ float wsum[4];
    const int lane = threadIdx.x & 63;
    const int w    = threadIdx.x >> 6;
    if (lane == 0) wsum[w] = s;
    __syncthreads();
    if (threadIdx.x == 0)
        *out = wsum[0] + wsum[1] + wsum[2] + wsum[3];
}

extern "C" void kernel_launch(void* const* d_in, const int* in_sizes, int n_in,
                              void* d_out, int out_size, void* d_ws, size_t ws_size,
                              hipStream_t stream) {
    const float* pred  = (const float*)d_in[0];
    const float* yhat  = (const float*)d_in[1];
    const float* prior = (const float*)d_in[2];
    float* out      = (float*)d_out;
    float* partials = (float*)d_ws;   // 676 floats; overwritten every call

    detection_loss_partial<<<NBLK, 256, 0, stream>>>(pred, yhat, prior, partials);
    detection_loss_final<<<1, 256, 0, stream>>>(partials, out);
}